// Round 3
// baseline (1295.439 us; speedup 1.0000x reference)
//
#include <hip/hip_runtime.h>

typedef unsigned short u16;
typedef __bf16 bf16x8 __attribute__((ext_vector_type(8)));
typedef unsigned short u16x8 __attribute__((ext_vector_type(8)));
typedef unsigned short u16x4 __attribute__((ext_vector_type(4)));
typedef float f32x4 __attribute__((ext_vector_type(4)));

#define K_DIM 2048
#define BM 128
#define BN 128
#define BK 64

// async global->LDS, 16B per lane; lds ptr must be wave-uniform base (+lane*16 in HW)
#define GLL16(g, l) __builtin_amdgcn_global_load_lds( \
    (const __attribute__((address_space(1))) void*)(g), \
    (__attribute__((address_space(3))) void*)(l), 16, 0, 0)

__device__ __forceinline__ u16 f2bf(float f) {
    unsigned int u = __builtin_bit_cast(unsigned int, f);
    u = (u + 0x7fffu + ((u >> 16) & 1u)) >> 16;   // RNE
    return (u16)u;
}
__device__ __forceinline__ float bf2f(u16 h) {
    unsigned int u = ((unsigned int)h) << 16;
    return __builtin_bit_cast(float, u);
}
__device__ __forceinline__ float softplus_f(float v) {
    return fmaxf(v, 0.0f) + log1pf(expf(-fabsf(v)));
}

// ---------------- pack f32 -> bf16: x (32768 blocks) + 4 W's (4096 each) ----------------
__global__ void pack_all(const float* __restrict__ x,
                         const float* __restrict__ Wq, const float* __restrict__ Wk,
                         const float* __restrict__ Wsq, const float* __restrict__ Wsk,
                         u16* __restrict__ xb, u16* __restrict__ wb) {
    int b = blockIdx.x;
    const float* src; u16* dst; size_t i;
    if (b < 32768) {
        src = x; dst = xb;
        i = (size_t)b * 256 + threadIdx.x;
    } else {
        int w  = (b - 32768) >> 12;        // 0..3 (block-uniform)
        int bb = (b - 32768) & 4095;
        src = (w < 2) ? ((w == 0) ? Wq : Wk) : ((w == 2) ? Wsq : Wsk);
        dst = wb + (size_t)w * 4194304;
        i = (size_t)bb * 256 + threadIdx.x;
    }
    float4 v = ((const float4*)src)[i];
    u16x4 o;
    o[0] = f2bf(v.x); o[1] = f2bf(v.y); o[2] = f2bf(v.z); o[3] = f2bf(v.w);
    ((u16x4*)dst)[i] = o;
}

// ---------------- fused GEMM: C = A * B^T, BK=64, swizzled LDS ----------------
// LDS tile row = 64 bf16 = 8 chunks of 16B. Chunk (row r, k-chunk q) stored at
// in-row position p = (q + (r&7)) & 7  -> ds_read_b128 conflict-free per 16-lane phase.
__global__ __launch_bounds__(256) void gemm_fused(
    const u16* __restrict__ xb, const u16* __restrict__ wb,
    u16* __restrict__ qb, u16* __restrict__ kb,
    u16* __restrict__ sqb, u16* __restrict__ skb)
{
    __shared__ u16 Als[BM * BK];   // 16 KB
    __shared__ u16 Bls[BM * BK];   // 16 KB
    __shared__ float ss[BM];

    const int tid  = threadIdx.x;
    const int lane = tid & 63;
    const int wave = tid >> 6;
    const int wm = wave >> 1;   // 2x2 wave grid, each wave 64x64
    const int wn = wave & 1;
    const int gm0 = blockIdx.y * BM;
    const int gn0 = blockIdx.x * BN;

    // staging: pass P (0..3), thread tid writes LDS slot P*256+tid (16B slots).
    // slot row = P*32 + (tid>>3), in-row pos p = tid&7; stored global chunk
    // q = (p - row) & 7 = ((tid&7) - ((tid>>3)&7)) & 7   (32 = 0 mod 8).
    const int r0 = tid >> 3;                             // 0..31
    const int qs = ((tid & 7) - ((tid >> 3) & 7)) & 7;
    const int kc = qs * 8;                               // u16 offset in 64-elem k-slice
    const u16* gA = xb + (size_t)(gm0 + r0) * K_DIM + kc;
    const u16* gB = wb + (size_t)(gn0 + r0) * K_DIM + kc;
    const size_t rstep = (size_t)32 * K_DIM;             // 32 rows, u16 units
    char* lA = (char*)Als + wave * 1024;
    char* lB = (char*)Bls + wave * 1024;

    f32x4 acc[4][4] = {};

    const int mr = lane & 15;
    const int q  = lane >> 4;
    const int m7 = mr & 7;
    const int pos0 = ((q + m7) & 7) * 8;        // subk 0 read position (u16)
    const int pos1 = ((q + m7 + 4) & 7) * 8;    // subk 1
    const int abase = (wm * 64 + mr) * 64;      // + i*1024
    const int bbase = (wn * 64 + mr) * 64;      // + j*1024

    for (int kt = 0; kt < K_DIM / BK; ++kt) {
        GLL16(gA,             lA);
        GLL16(gA + rstep,     lA + 4096);
        GLL16(gA + 2 * rstep, lA + 8192);
        GLL16(gA + 3 * rstep, lA + 12288);
        GLL16(gB,             lB);
        GLL16(gB + rstep,     lB + 4096);
        GLL16(gB + 2 * rstep, lB + 8192);
        GLL16(gB + 3 * rstep, lB + 12288);
        gA += BK; gB += BK;
        __syncthreads();   // drains vmcnt(0) then barrier

        bf16x8 a[4], b[4];
#pragma unroll
        for (int i = 0; i < 4; ++i)
            a[i] = __builtin_bit_cast(bf16x8, *(const u16x8*)&Als[abase + i * 1024 + pos0]);
#pragma unroll
        for (int j = 0; j < 4; ++j)
            b[j] = __builtin_bit_cast(bf16x8, *(const u16x8*)&Bls[bbase + j * 1024 + pos0]);
#pragma unroll
        for (int i = 0; i < 4; ++i)
#pragma unroll
            for (int j = 0; j < 4; ++j)
                acc[i][j] = __builtin_amdgcn_mfma_f32_16x16x32_bf16(a[i], b[j], acc[i][j], 0, 0, 0);
#pragma unroll
        for (int i = 0; i < 4; ++i)
            a[i] = __builtin_bit_cast(bf16x8, *(const u16x8*)&Als[abase + i * 1024 + pos1]);
#pragma unroll
        for (int j = 0; j < 4; ++j)
            b[j] = __builtin_bit_cast(bf16x8, *(const u16x8*)&Bls[bbase + j * 1024 + pos1]);
#pragma unroll
        for (int i = 0; i < 4; ++i)
#pragma unroll
            for (int j = 0; j < 4; ++j)
                acc[i][j] = __builtin_amdgcn_mfma_f32_16x16x32_bf16(a[i], b[j], acc[i][j], 0, 0, 0);
        __syncthreads();
    }

    // ---------------- epilogue ----------------
    const int which = gn0 >> 11;          // 0:q 1:k 2:sq 3:sk (block-uniform)
    if (tid < BM) ss[tid] = 0.0f;
    __syncthreads();

    const int mbase = wm * 64 + (lane >> 4) * 4;     // + i*16 + r
    const int col0  = (gn0 & 2047) + wn * 64 + (lane & 15);  // + j*16

    if (which < 2) {
        // per-row sum of squares over the tile's 128 cols (== one head, Dh=128)
#pragma unroll
        for (int i = 0; i < 4; ++i) {
#pragma unroll
            for (int r = 0; r < 4; ++r) {
                float sv = acc[i][0][r] * acc[i][0][r] + acc[i][1][r] * acc[i][1][r]
                         + acc[i][2][r] * acc[i][2][r] + acc[i][3][r] * acc[i][3][r];
                sv += __shfl_xor(sv, 1, 64);
                sv += __shfl_xor(sv, 2, 64);
                sv += __shfl_xor(sv, 4, 64);
                sv += __shfl_xor(sv, 8, 64);
                if ((lane & 15) == 0) atomicAdd(&ss[mbase + i * 16 + r], sv);
            }
        }
        __syncthreads();
    }

    u16* ob = (which == 0) ? qb : (which == 1) ? kb : (which == 2) ? sqb : skb;
#pragma unroll
    for (int i = 0; i < 4; ++i) {
#pragma unroll
        for (int r = 0; r < 4; ++r) {
            int m = mbase + i * 16 + r;
            size_t rowbase = (size_t)(gm0 + m) * 2048;
            float scale = 1.0f;
            if (which < 2)
                scale = rsqrtf(ss[m] * (1.0f / 128.0f) + 1.1920929e-07f);
#pragma unroll
            for (int j = 0; j < 4; ++j) {
                float v = acc[i][j][r];
                v = (which < 2) ? v * scale : softplus_f(v);
                ob[rowbase + col0 + j * 16] = f2bf(v);
            }
        }
    }
}

// ---------------- interp + multiply, 8 elems/thread ----------------
__global__ void interp_mul(const u16* __restrict__ qb, const u16* __restrict__ kb,
                           const u16* __restrict__ sqb, const u16* __restrict__ skb,
                           float* __restrict__ out)
{
    size_t base = ((size_t)blockIdx.x * 256 + threadIdx.x) * 8;   // 16384*256*8 = 2^25
    int c0 = (int)(base & 2047);
    size_t bt = base >> 11;
    int t = (int)(bt & 4095);
    float tf = (float)t;

    u16x8 sq8 = *(const u16x8*)(sqb + base);
    u16x8 sk8 = *(const u16x8*)(skb + base);
    size_t rb = (base >> 23) << 23;   // b * T * 2048

    float res[8];
#pragma unroll
    for (int e = 0; e < 8; ++e) {
        float pq = fminf(fmaxf(tf - bf2f(sq8[e]), 0.0f), tf);
        float pk = fminf(fmaxf(tf - bf2f(sk8[e]), 0.0f), tf);
        float pqf = floorf(pq), pkf = floorf(pk);
        int q0i = (int)pqf, k0i = (int)pkf;
        int q1i = min(q0i + 1, 4095), k1i = min(k0i + 1, 4095);
        float fq = pq - pqf, fk = pk - pkf;
        size_t o = rb + (size_t)(c0 + e);
        float q0 = bf2f(qb[o + ((size_t)q0i << 11)]);
        float q1 = bf2f(qb[o + ((size_t)q1i << 11)]);
        float k0 = bf2f(kb[o + ((size_t)k0i << 11)]);
        float k1 = bf2f(kb[o + ((size_t)k1i << 11)]);
        res[e] = (q0 + (q1 - q0) * fq) * (k0 + (k1 - k0) * fk);
    }
    float4* op = (float4*)(out + base);
    op[0] = make_float4(res[0], res[1], res[2], res[3]);
    op[1] = make_float4(res[4], res[5], res[6], res[7]);
}

extern "C" void kernel_launch(void* const* d_in, const int* in_sizes, int n_in,
                              void* d_out, int out_size, void* d_ws, size_t ws_size,
                              hipStream_t stream) {
    const float* x   = (const float*)d_in[0];
    const float* Wq  = (const float*)d_in[1];
    const float* Wk  = (const float*)d_in[2];
    const float* Wsq = (const float*)d_in[3];
    const float* Wsk = (const float*)d_in[4];
    float* out = (float*)d_out;

    // ws layout (bytes): xb 64MB | wb 32MB | qb 64MB | kb 64MB | sqb 64MB | skb 64MB = 352MB
    const size_t NEED = 369098752;
    if (ws_size < NEED) return;   // loud failure -> ws too small
    char* ws = (char*)d_ws;
    u16* xb  = (u16*)(ws);
    u16* wb  = (u16*)(ws + 67108864);
    u16* qb  = (u16*)(ws + 100663296);
    u16* kb  = (u16*)(ws + 167772160);
    u16* sqb = (u16*)(ws + 234881024);
    u16* skb = (u16*)(ws + 301989888);

    pack_all<<<49152, 256, 0, stream>>>(x, Wq, Wk, Wsq, Wsk, xb, wb);

    dim3 ggrid(64, 128);   // N tiles x M tiles
    gemm_fused<<<ggrid, 256, 0, stream>>>(xb, wb, qb, kb, sqb, skb);

    interp_mul<<<16384, 256, 0, stream>>>(qb, kb, sqb, skb, out);
}